// Round 5
// baseline (434.578 us; speedup 1.0000x reference)
//
#include <hip/hip_runtime.h>
#include <cstdint>
#include <cstddef>

// ---------------- problem constants (from setup_inputs) ----------------
constexpr int Nn   = 50000;            // nodes
constexpr int Ee   = 800000;           // edges (without self loops)
constexpr int ETot = Ee + Nn;          // 850000 with self loops
constexpr int H1   = 8;                // heads layer 1
constexpr int C1h  = 32;               // channels/head layer 1
constexpr int HC1  = 256;              // H1*C1h
constexpr int C2   = 40;               // classes (layer 2, 1 head)
constexpr float SLOPE = 0.2f;          // leaky_relu negative slope
constexpr int NB_SCAN = (Nn + 255) / 256;   // 196 scan blocks

typedef __attribute__((ext_vector_type(8))) short bf16x8;   // 8 bf16 (4 VGPRs)
typedef __attribute__((ext_vector_type(4))) float f32x4;    // MFMA accumulator

__device__ __forceinline__ ushort f2bf(float f) {           // RNE f32->bf16
    uint u = __float_as_uint(f);
    u += 0x7fffu + ((u >> 16) & 1u);
    return (ushort)(u >> 16);
}
__device__ __forceinline__ float bf2f(ushort b) {
    return __uint_as_float(((uint)b) << 16);
}

// ================= split x into bf16 hi/lo =================
__global__ void k_split(const float* __restrict__ x, ushort* __restrict__ hi,
                        ushort* __restrict__ lo, int n4) {
    int t = blockIdx.x * blockDim.x + threadIdx.x;
    if (t >= n4) return;
    float4 v = *(const float4*)(x + (size_t)t * 4);
    ushort4 h, l;
    h.x = f2bf(v.x); l.x = f2bf(v.x - bf2f(h.x));
    h.y = f2bf(v.y); l.y = f2bf(v.y - bf2f(h.y));
    h.z = f2bf(v.z); l.z = f2bf(v.z - bf2f(h.z));
    h.w = f2bf(v.w); l.w = f2bf(v.w - bf2f(h.w));
    *(ushort4*)(hi + (size_t)t * 4) = h;
    *(ushort4*)(lo + (size_t)t * 4) = l;
}

// ======= W1 [256][256] -> WT' [256 cols][768 k'] bf16: [Whi; Whi; Wlo] =======
__global__ void k_wsplit(const float* __restrict__ W, ushort* __restrict__ WT) {
    int idx = blockIdx.x * blockDim.x + threadIdx.x;   // 65536
    if (idx >= 256 * 256) return;
    int k = idx & 255, col = idx >> 8;
    float w = W[(size_t)k * 256 + col];
    ushort h = f2bf(w), l = f2bf(w - bf2f(h));
    WT[(size_t)col * 768 + k]       = h;
    WT[(size_t)col * 768 + 256 + k] = h;
    WT[(size_t)col * 768 + 512 + k] = l;
}

// ================= CSR build (histogram -> scan -> scatter) =================
__global__ void k_hist(const int* __restrict__ dstA, int* __restrict__ counts) {
    int e = blockIdx.x * blockDim.x + threadIdx.x;
    if (e >= ETot) return;
    int d = (e < Ee) ? dstA[e] : e - Ee;
    atomicAdd(&counts[d], 1);
}

__global__ __launch_bounds__(256) void k_scan_block(const int* __restrict__ counts,
                                                    int* __restrict__ exsc,
                                                    int* __restrict__ bsum) {
    __shared__ int sm[256];
    int i = blockIdx.x * 256 + threadIdx.x;
    int v = (i < Nn) ? counts[i] : 0;
    sm[threadIdx.x] = v;
    __syncthreads();
#pragma unroll
    for (int off = 1; off < 256; off <<= 1) {
        int t = (threadIdx.x >= off) ? sm[threadIdx.x - off] : 0;
        __syncthreads();
        sm[threadIdx.x] += t;
        __syncthreads();
    }
    if (i < Nn) exsc[i] = sm[threadIdx.x] - v;
    if (threadIdx.x == 255) bsum[blockIdx.x] = sm[255];
}

__global__ __launch_bounds__(256) void k_scan_top(const int* __restrict__ bsum,
                                                  int* __restrict__ boff) {
    __shared__ int sm[256];
    int t = threadIdx.x;
    int v = (t < NB_SCAN) ? bsum[t] : 0;
    sm[t] = v;
    __syncthreads();
#pragma unroll
    for (int off = 1; off < 256; off <<= 1) {
        int x = (t >= off) ? sm[t - off] : 0;
        __syncthreads();
        sm[t] += x;
        __syncthreads();
    }
    if (t < NB_SCAN) boff[t] = sm[t] - v;
}

__global__ void k_finalize_off(const int* __restrict__ exsc, const int* __restrict__ boff,
                               int* __restrict__ row_off, int* __restrict__ cursor) {
    int i = blockIdx.x * blockDim.x + threadIdx.x;
    if (i < Nn) {
        int r = exsc[i] + boff[i >> 8];
        row_off[i] = r;
        cursor[i] = r;
    }
    if (i == 0) row_off[Nn] = ETot;
}

__global__ void k_scatter(const int* __restrict__ srcA, const int* __restrict__ dstA,
                          int* __restrict__ cursor, int* __restrict__ csr_src) {
    int e = blockIdx.x * blockDim.x + threadIdx.x;
    if (e >= ETot) return;
    int s, d;
    if (e < Ee) { s = srcA[e]; d = dstA[e]; } else { s = e - Ee; d = s; }
    int pos = atomicAdd(&cursor[d], 1);
    csr_src[pos] = s;
}

// ========== GEMM1 (MFMA bf16, split precision): [M,768']x[768',256] ==========
// A' = [xhi | xlo | xhi], B' = WT' = [Whi; Whi; Wlo] (WT stored [256 cols][768]).
// Tile 64x256 (full width: A fetched exactly once), BK=32, 4 waves; each wave
// computes 64x64 via 16x16x32 MFMA -> 16 MFMA / wave / K-step (2x R4 density).
__global__ __launch_bounds__(256) void k_gemm1_mfma(const ushort* __restrict__ xhi,
                                                    const ushort* __restrict__ xlo,
                                                    const ushort* __restrict__ WT,
                                                    ushort* __restrict__ h1b, int M) {
    constexpr int BM = 64, BK = 32, KD = 768;
    __shared__ __align__(16) ushort Al[BM * BK];    //  4 KB: (kc*64 + row)*8
    __shared__ __align__(16) ushort Bl[256 * BK];   // 16 KB: (kc*256 + col)*8
    const int tid = threadIdx.x;
    const int bm = blockIdx.x * BM;
    const int lane = tid & 63;
    const int w = tid >> 6;                  // wave id = column block (w*64)
    const int l16 = lane & 15, lk = lane >> 4;

    // staging: A chunk (kc=tid>>6, row=tid&63) -> lds addr tid*8 (linear)
    const int akc = tid >> 6, arow_ = tid & 63;
    int arow = bm + arow_; arow = arow < M ? arow : M - 1;

    f32x4 acc[4][4] = {};
    uint4 pa, pb[4];
    auto load_tile = [&](int k0) {
        const ushort* asrc; int ks;
        if (k0 < 256)      { asrc = xhi; ks = k0; }
        else if (k0 < 512) { asrc = xlo; ks = k0 - 256; }
        else               { asrc = xhi; ks = k0 - 512; }
        pa = *(const uint4*)(asrc + (size_t)arow * 256 + ks + akc * 8);
#pragma unroll
        for (int j = 0; j < 4; j++)      // col = tid, kc = j (128 B contiguous)
            pb[j] = *(const uint4*)(WT + (size_t)tid * KD + k0 + j * 8);
    };
    load_tile(0);
    for (int k0 = 0; k0 < KD; k0 += BK) {
        __syncthreads();                      // prev iter's frag reads done
        *(uint4*)(Al + tid * 8) = pa;
#pragma unroll
        for (int j = 0; j < 4; j++)
            *(uint4*)(Bl + (j * 256 + tid) * 8) = pb[j];
        __syncthreads();
        if (k0 + BK < KD) load_tile(k0 + BK); // prefetch next tile into regs
        bf16x8 a[4], b[4];
#pragma unroll
        for (int m = 0; m < 4; m++)
            a[m] = *(const bf16x8*)(Al + (lk * 64 + m * 16 + l16) * 8);
#pragma unroll
        for (int n = 0; n < 4; n++)
            b[n] = *(const bf16x8*)(Bl + (lk * 256 + w * 64 + n * 16 + l16) * 8);
#pragma unroll
        for (int m = 0; m < 4; m++)
#pragma unroll
            for (int n = 0; n < 4; n++)
                acc[m][n] = __builtin_amdgcn_mfma_f32_16x16x32_bf16(a[m], b[n], acc[m][n], 0, 0, 0);
    }
    // epilogue: C row = lk*4 + j (+m*16), col = l16 (+w*64 + n*16)
#pragma unroll
    for (int m = 0; m < 4; m++) {
#pragma unroll
        for (int j = 0; j < 4; j++) {
            int row = bm + m * 16 + lk * 4 + j;
            if (row < M) {
#pragma unroll
                for (int n = 0; n < 4; n++)
                    h1b[(size_t)row * 256 + w * 64 + n * 16 + l16] = f2bf(acc[m][n][j]);
            }
        }
    }
}

// ---------------- per-node attention coefficients (bf16 h) ----------------
template <int H, int C>
__global__ void k_alpha_b(const ushort* __restrict__ h, const float* __restrict__ a_s,
                          const float* __restrict__ a_d, float* __restrict__ asrc,
                          float* __restrict__ adst, int N) {
    __shared__ float ls[H * C], ldd[H * C];
    for (int i = threadIdx.x; i < H * C; i += blockDim.x) { ls[i] = a_s[i]; ldd[i] = a_d[i]; }
    __syncthreads();
    int t = blockIdx.x * blockDim.x + threadIdx.x;
    if (t >= N * H) return;
    int n = t / H, hh = t % H;
    const ushort* row = h + (size_t)n * (H * C) + hh * C;
    float s = 0.f, dd = 0.f;
#pragma unroll
    for (int c = 0; c < C; c += 4) {
        ushort4 v = *(const ushort4*)(row + c);
        float f0 = bf2f(v.x), f1 = bf2f(v.y), f2 = bf2f(v.z), f3 = bf2f(v.w);
        s  += f0 * ls[hh * C + c] + f1 * ls[hh * C + c + 1] +
              f2 * ls[hh * C + c + 2] + f3 * ls[hh * C + c + 3];
        dd += f0 * ldd[hh * C + c] + f1 * ldd[hh * C + c + 1] +
              f2 * ldd[hh * C + c + 2] + f3 * ldd[hh * C + c + 3];
    }
    asrc[t] = s;
    adst[t] = dd;
}

// ---------------- per-node attention coefficients (f32 h, layer 2) ----------
template <int H, int C>
__global__ void k_alpha(const float* __restrict__ h, const float* __restrict__ a_s,
                        const float* __restrict__ a_d, float* __restrict__ asrc,
                        float* __restrict__ adst, int N) {
    __shared__ float ls[H * C], ldd[H * C];
    for (int i = threadIdx.x; i < H * C; i += blockDim.x) { ls[i] = a_s[i]; ldd[i] = a_d[i]; }
    __syncthreads();
    int t = blockIdx.x * blockDim.x + threadIdx.x;
    if (t >= N * H) return;
    int n = t / H, hh = t % H;
    const float* row = h + (size_t)n * (H * C) + hh * C;
    float s = 0.f, dd = 0.f;
#pragma unroll
    for (int c = 0; c < C; c += 4) {
        float4 v = *(const float4*)(row + c);
        s  += v.x * ls[hh * C + c] + v.y * ls[hh * C + c + 1] +
              v.z * ls[hh * C + c + 2] + v.w * ls[hh * C + c + 3];
        dd += v.x * ldd[hh * C + c] + v.y * ldd[hh * C + c + 1] +
              v.z * ldd[hh * C + c + 2] + v.w * ldd[hh * C + c + 3];
    }
    asrc[t] = s;
    adst[t] = dd;
}

// ======== layer-1 aggregation: wave/node, CSR gather, 4-wide unrolled ========
__global__ __launch_bounds__(256) void k_gat_aggr1(const int* __restrict__ row_off,
                                                   const int* __restrict__ csr_src,
                                                   const float* __restrict__ asrc,
                                                   const float* __restrict__ adst,
                                                   const ushort* __restrict__ h1b,
                                                   const float* __restrict__ bias,
                                                   float* __restrict__ out) {
    int wid = (blockIdx.x * 256 + threadIdx.x) >> 6;   // node id
    if (wid >= Nn) return;
    int lane = threadIdx.x & 63;
    int head = lane >> 3;
    int c0 = head * C1h + ((lane & 7) << 2);
    int beg = row_off[wid], end = row_off[wid + 1];
    float ad = adst[(size_t)wid * H1 + head];
    float4 acc = make_float4(0.f, 0.f, 0.f, 0.f);
    float sump = 0.f;
    int i = beg;
    for (; i + 3 < end; i += 4) {
        int s0 = csr_src[i], s1 = csr_src[i + 1], s2 = csr_src[i + 2], s3 = csr_src[i + 3];
        float a0 = asrc[(size_t)s0 * H1 + head], a1 = asrc[(size_t)s1 * H1 + head];
        float a2 = asrc[(size_t)s2 * H1 + head], a3 = asrc[(size_t)s3 * H1 + head];
        ushort4 v0 = *(const ushort4*)(h1b + (size_t)s0 * HC1 + c0);
        ushort4 v1 = *(const ushort4*)(h1b + (size_t)s1 * HC1 + c0);
        ushort4 v2 = *(const ushort4*)(h1b + (size_t)s2 * HC1 + c0);
        ushort4 v3 = *(const ushort4*)(h1b + (size_t)s3 * HC1 + c0);
        float l0 = a0 + ad; l0 = l0 > 0.f ? l0 : SLOPE * l0;
        float l1 = a1 + ad; l1 = l1 > 0.f ? l1 : SLOPE * l1;
        float l2 = a2 + ad; l2 = l2 > 0.f ? l2 : SLOPE * l2;
        float l3 = a3 + ad; l3 = l3 > 0.f ? l3 : SLOPE * l3;
        float p0 = __expf(l0), p1 = __expf(l1), p2 = __expf(l2), p3 = __expf(l3);
        sump += (p0 + p1) + (p2 + p3);
        acc.x += p0 * bf2f(v0.x) + p1 * bf2f(v1.x) + p2 * bf2f(v2.x) + p3 * bf2f(v3.x);
        acc.y += p0 * bf2f(v0.y) + p1 * bf2f(v1.y) + p2 * bf2f(v2.y) + p3 * bf2f(v3.y);
        acc.z += p0 * bf2f(v0.z) + p1 * bf2f(v1.z) + p2 * bf2f(v2.z) + p3 * bf2f(v3.z);
        acc.w += p0 * bf2f(v0.w) + p1 * bf2f(v1.w) + p2 * bf2f(v2.w) + p3 * bf2f(v3.w);
    }
    for (; i < end; i++) {
        int s = csr_src[i];
        float l = asrc[(size_t)s * H1 + head] + ad;
        l = l > 0.f ? l : SLOPE * l;
        float pe = __expf(l);
        sump += pe;
        ushort4 v = *(const ushort4*)(h1b + (size_t)s * HC1 + c0);
        acc.x += pe * bf2f(v.x); acc.y += pe * bf2f(v.y);
        acc.z += pe * bf2f(v.z); acc.w += pe * bf2f(v.w);
    }
    float inv = 1.f / sump;
    float4 b4 = *(const float4*)(bias + c0);
    float4 r;
    r.x = acc.x * inv + b4.x; r.y = acc.y * inv + b4.y;
    r.z = acc.z * inv + b4.z; r.w = acc.w * inv + b4.w;
    r.x = r.x > 0.f ? r.x : __expf(r.x) - 1.f;
    r.y = r.y > 0.f ? r.y : __expf(r.y) - 1.f;
    r.z = r.z > 0.f ? r.z : __expf(r.z) - 1.f;
    r.w = r.w > 0.f ? r.w : __expf(r.w) - 1.f;
    *(float4*)(out + (size_t)wid * HC1 + c0) = r;
}

// ---------------- GEMM2: [M,256] x [256,40] -> [M,40] (fp32) ----------------
__global__ __launch_bounds__(256) void k_gemm2(const float* __restrict__ A,
                                               const float* __restrict__ B,
                                               float* __restrict__ C, int M) {
    constexpr int K = 256, NC = 40, BM = 32, BK = 32;
    __shared__ float Ws[K * NC];
    __shared__ float As[BM][BK];
    const int tid = threadIdx.x;
    for (int i = tid; i < K * NC; i += 256) Ws[i] = B[i];
    const int bm = blockIdx.x * BM;
    const int r = tid >> 3, g = tid & 7;
    float acc[5] = {};
    for (int k0 = 0; k0 < K; k0 += BK) {
        int ko = (tid & 7) << 2;
        float4 v = make_float4(0.f, 0.f, 0.f, 0.f);
        if (bm + r < M) v = *(const float4*)(A + (size_t)(bm + r) * K + k0 + ko);
        *(float4*)&As[r][ko] = v;
        __syncthreads();
#pragma unroll
        for (int kk = 0; kk < BK; kk++) {
            float a = As[r][kk];
#pragma unroll
            for (int j = 0; j < 5; j++) acc[j] += a * Ws[(k0 + kk) * NC + g * 5 + j];
        }
        __syncthreads();
    }
    if (bm + r < M) {
#pragma unroll
        for (int j = 0; j < 5; j++) C[(size_t)(bm + r) * NC + g * 5 + j] = acc[j];
    }
}

// ======== layer-2 aggregation: wave/node, lanes 0..39, 4-wide unrolled ======
__global__ __launch_bounds__(256) void k_gat_aggr2(const int* __restrict__ row_off,
                                                   const int* __restrict__ csr_src,
                                                   const float* __restrict__ asrc,
                                                   const float* __restrict__ adst,
                                                   const float* __restrict__ h2,
                                                   const float* __restrict__ bias,
                                                   float* __restrict__ out) {
    int wid = (blockIdx.x * 256 + threadIdx.x) >> 6;
    if (wid >= Nn) return;
    int lane = threadIdx.x & 63;
    int cl = lane < C2 ? lane : C2 - 1;            // clamp: lanes 40..63 read c39
    int beg = row_off[wid], end = row_off[wid + 1];
    float ad = adst[wid];
    float acc = 0.f, sump = 0.f;
    int i = beg;
    for (; i + 3 < end; i += 4) {
        int s0 = csr_src[i], s1 = csr_src[i + 1], s2 = csr_src[i + 2], s3 = csr_src[i + 3];
        float a0 = asrc[s0], a1 = asrc[s1], a2 = asrc[s2], a3 = asrc[s3];
        float v0 = h2[(size_t)s0 * C2 + cl];
        float v1 = h2[(size_t)s1 * C2 + cl];
        float v2 = h2[(size_t)s2 * C2 + cl];
        float v3 = h2[(size_t)s3 * C2 + cl];
        float l0 = a0 + ad; l0 = l0 > 0.f ? l0 : SLOPE * l0;
        float l1 = a1 + ad; l1 = l1 > 0.f ? l1 : SLOPE * l1;
        float l2 = a2 + ad; l2 = l2 > 0.f ? l2 : SLOPE * l2;
        float l3 = a3 + ad; l3 = l3 > 0.f ? l3 : SLOPE * l3;
        float p0 = __expf(l0), p1 = __expf(l1), p2 = __expf(l2), p3 = __expf(l3);
        sump += (p0 + p1) + (p2 + p3);
        acc += p0 * v0 + p1 * v1 + p2 * v2 + p3 * v3;
    }
    for (; i < end; i++) {
        int s = csr_src[i];
        float l = asrc[s] + ad;
        l = l > 0.f ? l : SLOPE * l;
        float pe = __expf(l);
        sump += pe;
        acc += pe * h2[(size_t)s * C2 + cl];
    }
    if (lane < C2) out[(size_t)wid * C2 + lane] = acc / sump + bias[lane];
}

// ---------------- launch ----------------
extern "C" void kernel_launch(void* const* d_in, const int* in_sizes, int n_in,
                              void* d_out, int out_size, void* d_ws, size_t ws_size,
                              hipStream_t stream) {
    const float* x   = (const float*)d_in[0];
    const int*   ei  = (const int*)d_in[1];
    const float* w1  = (const float*)d_in[2];
    const float* as1 = (const float*)d_in[3];
    const float* ad1 = (const float*)d_in[4];
    const float* b1  = (const float*)d_in[5];
    const float* w2  = (const float*)d_in[6];
    const float* as2 = (const float*)d_in[7];
    const float* ad2 = (const float*)d_in[8];
    const float* b2  = (const float*)d_in[9];
    float* outp = (float*)d_out;

    const int* srcA = ei;
    const int* dstA = ei + Ee;

    char* W = (char*)d_ws;
    size_t o = 0;
    auto allocB = [&](size_t bytes) { void* p = W + o; o += (bytes + 255) & ~(size_t)255; return p; };

    ushort* xhi   = (ushort*)allocB((size_t)Nn * HC1 * 2);   // 25.6 MB
    ushort* xlo   = (ushort*)allocB((size_t)Nn * HC1 * 2);   // 25.6 MB
    float*  out1  = (float*)xhi;   // alias: reuses xhi+xlo after GEMM1
    ushort* wt    = (ushort*)allocB((size_t)256 * 768 * 2);
    ushort* h1b   = (ushort*)allocB((size_t)Nn * HC1 * 2);   // 25.6 MB
    float*  h2    = (float*)allocB((size_t)Nn * C2 * 4);
    float*  asrc1 = (float*)allocB((size_t)Nn * H1 * 4);
    float*  adst1 = (float*)allocB((size_t)Nn * H1 * 4);
    float*  asrc2 = (float*)allocB((size_t)Nn * 4);
    float*  adst2 = (float*)allocB((size_t)Nn * 4);
    int* counts   = (int*)allocB((size_t)Nn * 4);
    int* exsc     = (int*)allocB((size_t)Nn * 4);
    int* bsum     = (int*)allocB(256 * 4);
    int* boff     = (int*)allocB(256 * 4);
    int* row_off  = (int*)allocB((size_t)(Nn + 1) * 4);
    int* cursor   = (int*)allocB((size_t)Nn * 4);
    int* csr_src  = (int*)allocB((size_t)ETot * 4);

    // ---- input splits (bf16 hi/lo) ----
    k_split<<<(Nn * HC1 / 4 + 255) / 256, 256, 0, stream>>>(x, xhi, xlo, Nn * HC1 / 4);
    k_wsplit<<<(256 * 256 + 255) / 256, 256, 0, stream>>>(w1, wt);

    // ---- CSR build (graph shared by both layers) ----
    hipMemsetAsync(counts, 0, (size_t)Nn * sizeof(int), stream);
    k_hist<<<(ETot + 255) / 256, 256, 0, stream>>>(dstA, counts);
    k_scan_block<<<NB_SCAN, 256, 0, stream>>>(counts, exsc, bsum);
    k_scan_top<<<1, 256, 0, stream>>>(bsum, boff);
    k_finalize_off<<<(Nn + 255) / 256, 256, 0, stream>>>(exsc, boff, row_off, cursor);
    k_scatter<<<(ETot + 255) / 256, 256, 0, stream>>>(srcA, dstA, cursor, csr_src);

    // ---- layer 1 ----
    k_gemm1_mfma<<<(Nn + 63) / 64, 256, 0, stream>>>(xhi, xlo, wt, h1b, Nn);
    k_alpha_b<H1, C1h><<<(Nn * H1 + 255) / 256, 256, 0, stream>>>(h1b, as1, ad1, asrc1, adst1, Nn);
    k_gat_aggr1<<<(int)(((size_t)Nn * 64 + 255) / 256), 256, 0, stream>>>(
        row_off, csr_src, asrc1, adst1, h1b, b1, out1);

    // ---- layer 2 ----
    k_gemm2<<<(Nn + 31) / 32, 256, 0, stream>>>(out1, w2, h2, Nn);
    k_alpha<1, C2><<<(Nn + 255) / 256, 256, 0, stream>>>(h2, as2, ad2, asrc2, adst2, Nn);
    k_gat_aggr2<<<(int)(((size_t)Nn * 64 + 255) / 256), 256, 0, stream>>>(
        row_off, csr_src, asrc2, adst2, h2, b2, outp);
}

// Round 6
// 322.796 us; speedup vs baseline: 1.3463x; 1.3463x over previous
//
#include <hip/hip_runtime.h>
#include <cstdint>
#include <cstddef>

// ---------------- problem constants (from setup_inputs) ----------------
constexpr int Nn   = 50000;            // nodes
constexpr int Ee   = 800000;           // edges (without self loops)
constexpr int ETot = Ee + Nn;          // 850000 with self loops
constexpr int H1   = 8;                // heads layer 1
constexpr int C1h  = 32;               // channels/head layer 1
constexpr int HC1  = 256;              // H1*C1h
constexpr int C2   = 40;               // classes (layer 2, 1 head)
constexpr float SLOPE = 0.2f;          // leaky_relu negative slope
constexpr int NB_SCAN = (Nn + 255) / 256;   // 196 scan blocks

typedef __attribute__((ext_vector_type(8))) short bf16x8;   // 8 bf16 (4 VGPRs)
typedef __attribute__((ext_vector_type(4))) float f32x4;    // MFMA accumulator

__device__ __forceinline__ ushort f2bf(float f) {           // RNE f32->bf16
    uint u = __float_as_uint(f);
    u += 0x7fffu + ((u >> 16) & 1u);
    return (ushort)(u >> 16);
}
__device__ __forceinline__ float bf2f(ushort b) {
    return __uint_as_float(((uint)b) << 16);
}

// ================= split x into bf16 hi/lo =================
__global__ void k_split(const float* __restrict__ x, ushort* __restrict__ hi,
                        ushort* __restrict__ lo, int n4) {
    int t = blockIdx.x * blockDim.x + threadIdx.x;
    if (t >= n4) return;
    float4 v = *(const float4*)(x + (size_t)t * 4);
    ushort4 h, l;
    h.x = f2bf(v.x); l.x = f2bf(v.x - bf2f(h.x));
    h.y = f2bf(v.y); l.y = f2bf(v.y - bf2f(h.y));
    h.z = f2bf(v.z); l.z = f2bf(v.z - bf2f(h.z));
    h.w = f2bf(v.w); l.w = f2bf(v.w - bf2f(h.w));
    *(ushort4*)(hi + (size_t)t * 4) = h;
    *(ushort4*)(lo + (size_t)t * 4) = l;
}

// ==== W1 [256][256] -> WT2 packed MFMA-ready: (k'/8)*256 + col, inner k'%8 ====
// k' in [0,768): [Whi; Whi; Wlo].  B tile for any (k0,col-block) is contiguous.
__global__ void k_wsplit(const float* __restrict__ W, ushort* __restrict__ WT2) {
    int idx = blockIdx.x * blockDim.x + threadIdx.x;   // 65536
    if (idx >= 256 * 256) return;
    int k = idx >> 8, col = idx & 255;
    float w = W[(size_t)k * 256 + col];
    ushort h = f2bf(w), l = f2bf(w - bf2f(h));
    int kb = k >> 3, kr = k & 7;
    WT2[((size_t)(kb)      * 256 + col) * 8 + kr] = h;   // k' = k
    WT2[((size_t)(kb + 32) * 256 + col) * 8 + kr] = h;   // k' = k+256
    WT2[((size_t)(kb + 64) * 256 + col) * 8 + kr] = l;   // k' = k+512
}

// ================= CSR build (histogram -> scan -> scatter) =================
__global__ void k_hist(const int* __restrict__ dstA, int* __restrict__ counts) {
    int e = blockIdx.x * blockDim.x + threadIdx.x;
    if (e >= ETot) return;
    int d = (e < Ee) ? dstA[e] : e - Ee;
    atomicAdd(&counts[d], 1);
}

__global__ __launch_bounds__(256) void k_scan_block(const int* __restrict__ counts,
                                                    int* __restrict__ exsc,
                                                    int* __restrict__ bsum) {
    __shared__ int sm[256];
    int i = blockIdx.x * 256 + threadIdx.x;
    int v = (i < Nn) ? counts[i] : 0;
    sm[threadIdx.x] = v;
    __syncthreads();
#pragma unroll
    for (int off = 1; off < 256; off <<= 1) {
        int t = (threadIdx.x >= off) ? sm[threadIdx.x - off] : 0;
        __syncthreads();
        sm[threadIdx.x] += t;
        __syncthreads();
    }
    if (i < Nn) exsc[i] = sm[threadIdx.x] - v;
    if (threadIdx.x == 255) bsum[blockIdx.x] = sm[255];
}

__global__ __launch_bounds__(256) void k_scan_top(const int* __restrict__ bsum,
                                                  int* __restrict__ boff) {
    __shared__ int sm[256];
    int t = threadIdx.x;
    int v = (t < NB_SCAN) ? bsum[t] : 0;
    sm[t] = v;
    __syncthreads();
#pragma unroll
    for (int off = 1; off < 256; off <<= 1) {
        int x = (t >= off) ? sm[t - off] : 0;
        __syncthreads();
        sm[t] += x;
        __syncthreads();
    }
    if (t < NB_SCAN) boff[t] = sm[t] - v;
}

__global__ void k_finalize_off(const int* __restrict__ exsc, const int* __restrict__ boff,
                               int* __restrict__ row_off, int* __restrict__ cursor) {
    int i = blockIdx.x * blockDim.x + threadIdx.x;
    if (i < Nn) {
        int r = exsc[i] + boff[i >> 8];
        row_off[i] = r;
        cursor[i] = r;
    }
    if (i == 0) row_off[Nn] = ETot;
}

__global__ void k_scatter(const int* __restrict__ srcA, const int* __restrict__ dstA,
                          int* __restrict__ cursor, int* __restrict__ csr_src) {
    int e = blockIdx.x * blockDim.x + threadIdx.x;
    if (e >= ETot) return;
    int s, d;
    if (e < Ee) { s = srcA[e]; d = dstA[e]; } else { s = e - Ee; d = s; }
    int pos = atomicAdd(&cursor[d], 1);
    csr_src[pos] = s;
}

// ========== GEMM1 (MFMA bf16, split precision): [M,768']x[768',256] ==========
// Tile 128x128, BK=32, 4 waves each 64x64 (acc[4][4]) -> 16 MFMA/wave/K-step.
// B staging = contiguous copy from packed WT2 (lane-coalesced 16 B loads);
// A staging = (row=tid>>2, kc=tid&3): 64 B-line coalesced.
__global__ __launch_bounds__(256, 3) void k_gemm1_mfma(const ushort* __restrict__ xhi,
                                                       const ushort* __restrict__ xlo,
                                                       const ushort* __restrict__ WT2,
                                                       ushort* __restrict__ h1b, int M) {
    constexpr int BK = 32, KD = 768;
    __shared__ __align__(16) ushort As[128 * BK];   // (kc*128 + row)*8
    __shared__ __align__(16) ushort Bs[128 * BK];   // (kc*128 + col)*8
    const int tid = threadIdx.x;
    const int bm = blockIdx.x * 128, bn = blockIdx.y * 128;
    const int lane = tid & 63;
    const int wid = tid >> 6;
    const int wm = wid >> 1, wn = wid & 1;          // wave -> 64x64 quadrant
    const int l16 = lane & 15, lk = lane >> 4;

    // A staging slots: rows {ar, ar+64}, k-chunk akc
    const int akc = tid & 3, ar = tid >> 2;
    int arow0 = bm + ar;      arow0 = arow0 < M ? arow0 : M - 1;
    int arow1 = bm + ar + 64; arow1 = arow1 < M ? arow1 : M - 1;
    // B staging slots: cols {bcol, bcol+64}, k-chunk bkc
    const int bkc = tid >> 6, bcol = tid & 63;

    f32x4 acc[4][4] = {};
    uint4 pa0, pa1, pb0, pb1;
    auto load_tile = [&](int k0) {
        const ushort* asrc; int ks;
        if (k0 < 256)      { asrc = xhi; ks = k0; }
        else if (k0 < 512) { asrc = xlo; ks = k0 - 256; }
        else               { asrc = xhi; ks = k0 - 512; }
        pa0 = *(const uint4*)(asrc + (size_t)arow0 * 256 + ks + akc * 8);
        pa1 = *(const uint4*)(asrc + (size_t)arow1 * 256 + ks + akc * 8);
        size_t kb = (size_t)((k0 >> 3) + bkc) * 256;
        pb0 = *(const uint4*)(WT2 + (kb + bn + bcol) * 8);
        pb1 = *(const uint4*)(WT2 + (kb + bn + bcol + 64) * 8);
    };
    load_tile(0);
    for (int k0 = 0; k0 < KD; k0 += BK) {
        __syncthreads();                      // prev iter's frag reads done
        *(uint4*)(As + (akc * 128 + ar) * 8)        = pa0;
        *(uint4*)(As + (akc * 128 + ar + 64) * 8)   = pa1;
        *(uint4*)(Bs + (bkc * 128 + bcol) * 8)      = pb0;
        *(uint4*)(Bs + (bkc * 128 + bcol + 64) * 8) = pb1;
        __syncthreads();
        if (k0 + BK < KD) load_tile(k0 + BK); // prefetch next tile into regs
        bf16x8 a[4], b[4];
#pragma unroll
        for (int m = 0; m < 4; m++)
            a[m] = *(const bf16x8*)(As + (lk * 128 + wm * 64 + m * 16 + l16) * 8);
#pragma unroll
        for (int n = 0; n < 4; n++)
            b[n] = *(const bf16x8*)(Bs + (lk * 128 + wn * 64 + n * 16 + l16) * 8);
#pragma unroll
        for (int m = 0; m < 4; m++)
#pragma unroll
            for (int n = 0; n < 4; n++)
                acc[m][n] = __builtin_amdgcn_mfma_f32_16x16x32_bf16(a[m], b[n], acc[m][n], 0, 0, 0);
    }
    // epilogue: C row = lk*4 + j (+m*16), col = l16 (+n*16)
#pragma unroll
    for (int m = 0; m < 4; m++) {
#pragma unroll
        for (int j = 0; j < 4; j++) {
            int row = bm + wm * 64 + m * 16 + lk * 4 + j;
            if (row < M) {
#pragma unroll
                for (int n = 0; n < 4; n++)
                    h1b[(size_t)row * 256 + bn + wn * 64 + n * 16 + l16] = f2bf(acc[m][n][j]);
            }
        }
    }
}

// ---------------- per-node attention coefficients (bf16 h) ----------------
template <int H, int C>
__global__ void k_alpha_b(const ushort* __restrict__ h, const float* __restrict__ a_s,
                          const float* __restrict__ a_d, float* __restrict__ asrc,
                          float* __restrict__ adst, int N) {
    __shared__ float ls[H * C], ldd[H * C];
    for (int i = threadIdx.x; i < H * C; i += blockDim.x) { ls[i] = a_s[i]; ldd[i] = a_d[i]; }
    __syncthreads();
    int t = blockIdx.x * blockDim.x + threadIdx.x;
    if (t >= N * H) return;
    int n = t / H, hh = t % H;
    const ushort* row = h + (size_t)n * (H * C) + hh * C;
    float s = 0.f, dd = 0.f;
#pragma unroll
    for (int c = 0; c < C; c += 4) {
        ushort4 v = *(const ushort4*)(row + c);
        float f0 = bf2f(v.x), f1 = bf2f(v.y), f2 = bf2f(v.z), f3 = bf2f(v.w);
        s  += f0 * ls[hh * C + c] + f1 * ls[hh * C + c + 1] +
              f2 * ls[hh * C + c + 2] + f3 * ls[hh * C + c + 3];
        dd += f0 * ldd[hh * C + c] + f1 * ldd[hh * C + c + 1] +
              f2 * ldd[hh * C + c + 2] + f3 * ldd[hh * C + c + 3];
    }
    asrc[t] = s;
    adst[t] = dd;
}

// ---------------- per-node attention coefficients (f32 h, layer 2) ----------
template <int H, int C>
__global__ void k_alpha(const float* __restrict__ h, const float* __restrict__ a_s,
                        const float* __restrict__ a_d, float* __restrict__ asrc,
                        float* __restrict__ adst, int N) {
    __shared__ float ls[H * C], ldd[H * C];
    for (int i = threadIdx.x; i < H * C; i += blockDim.x) { ls[i] = a_s[i]; ldd[i] = a_d[i]; }
    __syncthreads();
    int t = blockIdx.x * blockDim.x + threadIdx.x;
    if (t >= N * H) return;
    int n = t / H, hh = t % H;
    const float* row = h + (size_t)n * (H * C) + hh * C;
    float s = 0.f, dd = 0.f;
#pragma unroll
    for (int c = 0; c < C; c += 4) {
        float4 v = *(const float4*)(row + c);
        s  += v.x * ls[hh * C + c] + v.y * ls[hh * C + c + 1] +
              v.z * ls[hh * C + c + 2] + v.w * ls[hh * C + c + 3];
        dd += v.x * ldd[hh * C + c] + v.y * ldd[hh * C + c + 1] +
              v.z * ldd[hh * C + c + 2] + v.w * ldd[hh * C + c + 3];
    }
    asrc[t] = s;
    adst[t] = dd;
}

// ======== layer-1 aggregation: wave/node, CSR gather, 4-wide unrolled ========
__global__ __launch_bounds__(256) void k_gat_aggr1(const int* __restrict__ row_off,
                                                   const int* __restrict__ csr_src,
                                                   const float* __restrict__ asrc,
                                                   const float* __restrict__ adst,
                                                   const ushort* __restrict__ h1b,
                                                   const float* __restrict__ bias,
                                                   float* __restrict__ out) {
    int wid = (blockIdx.x * 256 + threadIdx.x) >> 6;   // node id
    if (wid >= Nn) return;
    int lane = threadIdx.x & 63;
    int head = lane >> 3;
    int c0 = head * C1h + ((lane & 7) << 2);
    int beg = row_off[wid], end = row_off[wid + 1];
    float ad = adst[(size_t)wid * H1 + head];
    float4 acc = make_float4(0.f, 0.f, 0.f, 0.f);
    float sump = 0.f;
    int i = beg;
    for (; i + 3 < end; i += 4) {
        int s0 = csr_src[i], s1 = csr_src[i + 1], s2 = csr_src[i + 2], s3 = csr_src[i + 3];
        float a0 = asrc[(size_t)s0 * H1 + head], a1 = asrc[(size_t)s1 * H1 + head];
        float a2 = asrc[(size_t)s2 * H1 + head], a3 = asrc[(size_t)s3 * H1 + head];
        ushort4 v0 = *(const ushort4*)(h1b + (size_t)s0 * HC1 + c0);
        ushort4 v1 = *(const ushort4*)(h1b + (size_t)s1 * HC1 + c0);
        ushort4 v2 = *(const ushort4*)(h1b + (size_t)s2 * HC1 + c0);
        ushort4 v3 = *(const ushort4*)(h1b + (size_t)s3 * HC1 + c0);
        float l0 = a0 + ad; l0 = l0 > 0.f ? l0 : SLOPE * l0;
        float l1 = a1 + ad; l1 = l1 > 0.f ? l1 : SLOPE * l1;
        float l2 = a2 + ad; l2 = l2 > 0.f ? l2 : SLOPE * l2;
        float l3 = a3 + ad; l3 = l3 > 0.f ? l3 : SLOPE * l3;
        float p0 = __expf(l0), p1 = __expf(l1), p2 = __expf(l2), p3 = __expf(l3);
        sump += (p0 + p1) + (p2 + p3);
        acc.x += p0 * bf2f(v0.x) + p1 * bf2f(v1.x) + p2 * bf2f(v2.x) + p3 * bf2f(v3.x);
        acc.y += p0 * bf2f(v0.y) + p1 * bf2f(v1.y) + p2 * bf2f(v2.y) + p3 * bf2f(v3.y);
        acc.z += p0 * bf2f(v0.z) + p1 * bf2f(v1.z) + p2 * bf2f(v2.z) + p3 * bf2f(v3.z);
        acc.w += p0 * bf2f(v0.w) + p1 * bf2f(v1.w) + p2 * bf2f(v2.w) + p3 * bf2f(v3.w);
    }
    for (; i < end; i++) {
        int s = csr_src[i];
        float l = asrc[(size_t)s * H1 + head] + ad;
        l = l > 0.f ? l : SLOPE * l;
        float pe = __expf(l);
        sump += pe;
        ushort4 v = *(const ushort4*)(h1b + (size_t)s * HC1 + c0);
        acc.x += pe * bf2f(v.x); acc.y += pe * bf2f(v.y);
        acc.z += pe * bf2f(v.z); acc.w += pe * bf2f(v.w);
    }
    float inv = 1.f / sump;
    float4 b4 = *(const float4*)(bias + c0);
    float4 r;
    r.x = acc.x * inv + b4.x; r.y = acc.y * inv + b4.y;
    r.z = acc.z * inv + b4.z; r.w = acc.w * inv + b4.w;
    r.x = r.x > 0.f ? r.x : __expf(r.x) - 1.f;
    r.y = r.y > 0.f ? r.y : __expf(r.y) - 1.f;
    r.z = r.z > 0.f ? r.z : __expf(r.z) - 1.f;
    r.w = r.w > 0.f ? r.w : __expf(r.w) - 1.f;
    *(float4*)(out + (size_t)wid * HC1 + c0) = r;
}

// ---------------- GEMM2: [M,256] x [256,40] -> [M,40] (fp32) ----------------
__global__ __launch_bounds__(256) void k_gemm2(const float* __restrict__ A,
                                               const float* __restrict__ B,
                                               float* __restrict__ C, int M) {
    constexpr int K = 256, NC = 40, BM = 32, BK = 32;
    __shared__ float Ws[K * NC];
    __shared__ float As[BM][BK];
    const int tid = threadIdx.x;
    for (int i = tid; i < K * NC; i += 256) Ws[i] = B[i];
    const int bm = blockIdx.x * BM;
    const int r = tid >> 3, g = tid & 7;
    float acc[5] = {};
    for (int k0 = 0; k0 < K; k0 += BK) {
        int ko = (tid & 7) << 2;
        float4 v = make_float4(0.f, 0.f, 0.f, 0.f);
        if (bm + r < M) v = *(const float4*)(A + (size_t)(bm + r) * K + k0 + ko);
        *(float4*)&As[r][ko] = v;
        __syncthreads();
#pragma unroll
        for (int kk = 0; kk < BK; kk++) {
            float a = As[r][kk];
#pragma unroll
            for (int j = 0; j < 5; j++) acc[j] += a * Ws[(k0 + kk) * NC + g * 5 + j];
        }
        __syncthreads();
    }
    if (bm + r < M) {
#pragma unroll
        for (int j = 0; j < 5; j++) C[(size_t)(bm + r) * NC + g * 5 + j] = acc[j];
    }
}

// ======== layer-2 aggregation: wave/node, lanes 0..39, 4-wide unrolled ======
__global__ __launch_bounds__(256) void k_gat_aggr2(const int* __restrict__ row_off,
                                                   const int* __restrict__ csr_src,
                                                   const float* __restrict__ asrc,
                                                   const float* __restrict__ adst,
                                                   const float* __restrict__ h2,
                                                   const float* __restrict__ bias,
                                                   float* __restrict__ out) {
    int wid = (blockIdx.x * 256 + threadIdx.x) >> 6;
    if (wid >= Nn) return;
    int lane = threadIdx.x & 63;
    int cl = lane < C2 ? lane : C2 - 1;            // clamp: lanes 40..63 read c39
    int beg = row_off[wid], end = row_off[wid + 1];
    float ad = adst[wid];
    float acc = 0.f, sump = 0.f;
    int i = beg;
    for (; i + 3 < end; i += 4) {
        int s0 = csr_src[i], s1 = csr_src[i + 1], s2 = csr_src[i + 2], s3 = csr_src[i + 3];
        float a0 = asrc[s0], a1 = asrc[s1], a2 = asrc[s2], a3 = asrc[s3];
        float v0 = h2[(size_t)s0 * C2 + cl];
        float v1 = h2[(size_t)s1 * C2 + cl];
        float v2 = h2[(size_t)s2 * C2 + cl];
        float v3 = h2[(size_t)s3 * C2 + cl];
        float l0 = a0 + ad; l0 = l0 > 0.f ? l0 : SLOPE * l0;
        float l1 = a1 + ad; l1 = l1 > 0.f ? l1 : SLOPE * l1;
        float l2 = a2 + ad; l2 = l2 > 0.f ? l2 : SLOPE * l2;
        float l3 = a3 + ad; l3 = l3 > 0.f ? l3 : SLOPE * l3;
        float p0 = __expf(l0), p1 = __expf(l1), p2 = __expf(l2), p3 = __expf(l3);
        sump += (p0 + p1) + (p2 + p3);
        acc += p0 * v0 + p1 * v1 + p2 * v2 + p3 * v3;
    }
    for (; i < end; i++) {
        int s = csr_src[i];
        float l = asrc[s] + ad;
        l = l > 0.f ? l : SLOPE * l;
        float pe = __expf(l);
        sump += pe;
        acc += pe * h2[(size_t)s * C2 + cl];
    }
    if (lane < C2) out[(size_t)wid * C2 + lane] = acc / sump + bias[lane];
}

// ---------------- launch ----------------
extern "C" void kernel_launch(void* const* d_in, const int* in_sizes, int n_in,
                              void* d_out, int out_size, void* d_ws, size_t ws_size,
                              hipStream_t stream) {
    const float* x   = (const float*)d_in[0];
    const int*   ei  = (const int*)d_in[1];
    const float* w1  = (const float*)d_in[2];
    const float* as1 = (const float*)d_in[3];
    const float* ad1 = (const float*)d_in[4];
    const float* b1  = (const float*)d_in[5];
    const float* w2  = (const float*)d_in[6];
    const float* as2 = (const float*)d_in[7];
    const float* ad2 = (const float*)d_in[8];
    const float* b2  = (const float*)d_in[9];
    float* outp = (float*)d_out;

    const int* srcA = ei;
    const int* dstA = ei + Ee;

    char* W = (char*)d_ws;
    size_t o = 0;
    auto allocB = [&](size_t bytes) { void* p = W + o; o += (bytes + 255) & ~(size_t)255; return p; };

    ushort* xhi   = (ushort*)allocB((size_t)Nn * HC1 * 2);   // 25.6 MB
    ushort* xlo   = (ushort*)allocB((size_t)Nn * HC1 * 2);   // 25.6 MB
    float*  out1  = (float*)xhi;   // alias: reuses xhi+xlo after GEMM1
    ushort* wt2   = (ushort*)allocB((size_t)768 * 256 * 2);  // packed W'
    ushort* h1b   = (ushort*)allocB((size_t)Nn * HC1 * 2);   // 25.6 MB
    float*  h2    = (float*)allocB((size_t)Nn * C2 * 4);
    float*  asrc1 = (float*)allocB((size_t)Nn * H1 * 4);
    float*  adst1 = (float*)allocB((size_t)Nn * H1 * 4);
    float*  asrc2 = (float*)allocB((size_t)Nn * 4);
    float*  adst2 = (float*)allocB((size_t)Nn * 4);
    int* counts   = (int*)allocB((size_t)Nn * 4);
    int* exsc     = (int*)allocB((size_t)Nn * 4);
    int* bsum     = (int*)allocB(256 * 4);
    int* boff     = (int*)allocB(256 * 4);
    int* row_off  = (int*)allocB((size_t)(Nn + 1) * 4);
    int* cursor   = (int*)allocB((size_t)Nn * 4);
    int* csr_src  = (int*)allocB((size_t)ETot * 4);

    // ---- input splits (bf16 hi/lo, packed W) ----
    k_split<<<(Nn * HC1 / 4 + 255) / 256, 256, 0, stream>>>(x, xhi, xlo, Nn * HC1 / 4);
    k_wsplit<<<(256 * 256 + 255) / 256, 256, 0, stream>>>(w1, wt2);

    // ---- CSR build (graph shared by both layers) ----
    hipMemsetAsync(counts, 0, (size_t)Nn * sizeof(int), stream);
    k_hist<<<(ETot + 255) / 256, 256, 0, stream>>>(dstA, counts);
    k_scan_block<<<NB_SCAN, 256, 0, stream>>>(counts, exsc, bsum);
    k_scan_top<<<1, 256, 0, stream>>>(bsum, boff);
    k_finalize_off<<<(Nn + 255) / 256, 256, 0, stream>>>(exsc, boff, row_off, cursor);
    k_scatter<<<(ETot + 255) / 256, 256, 0, stream>>>(srcA, dstA, cursor, csr_src);

    // ---- layer 1 ----
    dim3 g1((Nn + 127) / 128, 2);
    k_gemm1_mfma<<<g1, 256, 0, stream>>>(xhi, xlo, wt2, h1b, Nn);
    k_alpha_b<H1, C1h><<<(Nn * H1 + 255) / 256, 256, 0, stream>>>(h1b, as1, ad1, asrc1, adst1, Nn);
    k_gat_aggr1<<<(int)(((size_t)Nn * 64 + 255) / 256), 256, 0, stream>>>(
        row_off, csr_src, asrc1, adst1, h1b, b1, out1);

    // ---- layer 2 ----
    k_gemm2<<<(Nn + 31) / 32, 256, 0, stream>>>(out1, w2, h2, Nn);
    k_alpha<1, C2><<<(Nn + 255) / 256, 256, 0, stream>>>(h2, as2, ad2, asrc2, adst2, Nn);
    k_gat_aggr2<<<(int)(((size_t)Nn * 64 + 255) / 256), 256, 0, stream>>>(
        row_off, csr_src, asrc2, adst2, h2, b2, outp);
}

// Round 7
// 293.279 us; speedup vs baseline: 1.4818x; 1.1006x over previous
//
#include <hip/hip_runtime.h>
#include <cstdint>
#include <cstddef>

// ---------------- problem constants (from setup_inputs) ----------------
constexpr int Nn   = 50000;            // nodes
constexpr int Ee   = 800000;           // edges (without self loops)
constexpr int ETot = Ee + Nn;          // 850000 with self loops
constexpr int H1   = 8;                // heads layer 1
constexpr int C1h  = 32;               // channels/head layer 1
constexpr int HC1  = 256;              // H1*C1h
constexpr int C2   = 40;               // classes (layer 2, 1 head)
constexpr float SLOPE = 0.2f;          // leaky_relu negative slope
constexpr int NB_SCAN = (Nn + 255) / 256;   // 196 scan blocks

typedef __attribute__((ext_vector_type(8))) short bf16x8;   // 8 bf16 (4 VGPRs)
typedef __attribute__((ext_vector_type(4))) float f32x4;    // MFMA accumulator

__device__ __forceinline__ ushort f2bf(float f) {           // RNE f32->bf16
    uint u = __float_as_uint(f);
    u += 0x7fffu + ((u >> 16) & 1u);
    return (ushort)(u >> 16);
}
__device__ __forceinline__ float bf2f(ushort b) {
    return __uint_as_float(((uint)b) << 16);
}

// ================= split x into bf16 hi/lo =================
__global__ void k_split(const float* __restrict__ x, ushort* __restrict__ hi,
                        ushort* __restrict__ lo, int n4) {
    int t = blockIdx.x * blockDim.x + threadIdx.x;
    if (t >= n4) return;
    float4 v = *(const float4*)(x + (size_t)t * 4);
    ushort4 h, l;
    h.x = f2bf(v.x); l.x = f2bf(v.x - bf2f(h.x));
    h.y = f2bf(v.y); l.y = f2bf(v.y - bf2f(h.y));
    h.z = f2bf(v.z); l.z = f2bf(v.z - bf2f(h.z));
    h.w = f2bf(v.w); l.w = f2bf(v.w - bf2f(h.w));
    *(ushort4*)(hi + (size_t)t * 4) = h;
    *(ushort4*)(lo + (size_t)t * 4) = l;
}

// ==== W1 [256][256] -> WT2 packed MFMA-ready: ((k'/8)*256 + col)*8 + k'%8 ====
// k' in [0,768): [Whi; Whi; Wlo] matching A' = [xhi | xlo | xhi].
__global__ void k_wsplit(const float* __restrict__ W, ushort* __restrict__ WT2) {
    int idx = blockIdx.x * blockDim.x + threadIdx.x;   // 65536
    if (idx >= 256 * 256) return;
    int k = idx >> 8, col = idx & 255;
    float w = W[(size_t)k * 256 + col];
    ushort h = f2bf(w), l = f2bf(w - bf2f(h));
    int kb = k >> 3, kr = k & 7;
    WT2[((size_t)(kb)      * 256 + col) * 8 + kr] = h;   // k' = k
    WT2[((size_t)(kb + 32) * 256 + col) * 8 + kr] = h;   // k' = k+256
    WT2[((size_t)(kb + 64) * 256 + col) * 8 + kr] = l;   // k' = k+512
}

// ==== W2 [256][40] -> packed [ (k'/8)*48 + col ]*8 + k'%8, cols 40..47 = 0 ====
__global__ void k_w2split(const float* __restrict__ W2, ushort* __restrict__ WT) {
    int idx = blockIdx.x * blockDim.x + threadIdx.x;   // 256*48
    if (idx >= 256 * 48) return;
    int k = idx / 48, col = idx % 48;
    float w = (col < C2) ? W2[(size_t)k * C2 + col] : 0.f;
    ushort h = f2bf(w), l = f2bf(w - bf2f(h));
    int kb = k >> 3, kr = k & 7;
    WT[((size_t)(kb)      * 48 + col) * 8 + kr] = h;
    WT[((size_t)(kb + 32) * 48 + col) * 8 + kr] = h;
    WT[((size_t)(kb + 64) * 48 + col) * 8 + kr] = l;
}

// ================= CSR build (histogram -> scan -> scatter) =================
__global__ void k_hist(const int* __restrict__ dstA, int* __restrict__ counts) {
    int e = blockIdx.x * blockDim.x + threadIdx.x;
    if (e >= ETot) return;
    int d = (e < Ee) ? dstA[e] : e - Ee;
    atomicAdd(&counts[d], 1);
}

__global__ __launch_bounds__(256) void k_scan_block(const int* __restrict__ counts,
                                                    int* __restrict__ exsc,
                                                    int* __restrict__ bsum) {
    __shared__ int sm[256];
    int i = blockIdx.x * 256 + threadIdx.x;
    int v = (i < Nn) ? counts[i] : 0;
    sm[threadIdx.x] = v;
    __syncthreads();
#pragma unroll
    for (int off = 1; off < 256; off <<= 1) {
        int t = (threadIdx.x >= off) ? sm[threadIdx.x - off] : 0;
        __syncthreads();
        sm[threadIdx.x] += t;
        __syncthreads();
    }
    if (i < Nn) exsc[i] = sm[threadIdx.x] - v;
    if (threadIdx.x == 255) bsum[blockIdx.x] = sm[255];
}

__global__ __launch_bounds__(256) void k_scan_top(const int* __restrict__ bsum,
                                                  int* __restrict__ boff) {
    __shared__ int sm[256];
    int t = threadIdx.x;
    int v = (t < NB_SCAN) ? bsum[t] : 0;
    sm[t] = v;
    __syncthreads();
#pragma unroll
    for (int off = 1; off < 256; off <<= 1) {
        int x = (t >= off) ? sm[t - off] : 0;
        __syncthreads();
        sm[t] += x;
        __syncthreads();
    }
    if (t < NB_SCAN) boff[t] = sm[t] - v;
}

__global__ void k_finalize_off(const int* __restrict__ exsc, const int* __restrict__ boff,
                               int* __restrict__ row_off, int* __restrict__ cursor) {
    int i = blockIdx.x * blockDim.x + threadIdx.x;
    if (i < Nn) {
        int r = exsc[i] + boff[i >> 8];
        row_off[i] = r;
        cursor[i] = r;
    }
    if (i == 0) row_off[Nn] = ETot;
}

__global__ void k_scatter(const int* __restrict__ srcA, const int* __restrict__ dstA,
                          int* __restrict__ cursor, int* __restrict__ csr_src) {
    int e = blockIdx.x * blockDim.x + threadIdx.x;
    if (e >= ETot) return;
    int s, d;
    if (e < Ee) { s = srcA[e]; d = dstA[e]; } else { s = e - Ee; d = s; }
    int pos = atomicAdd(&cursor[d], 1);
    csr_src[pos] = s;
}

// ========== GEMM1 (MFMA bf16, split precision): [M,768']x[768',256] ==========
// Tile 128x128, BK=32, 4 waves each 64x64 (acc[4][4]) -> 16 MFMA/wave/K-step.
__global__ __launch_bounds__(256, 3) void k_gemm1_mfma(const ushort* __restrict__ xhi,
                                                       const ushort* __restrict__ xlo,
                                                       const ushort* __restrict__ WT2,
                                                       ushort* __restrict__ h1b, int M) {
    constexpr int BK = 32, KD = 768;
    __shared__ __align__(16) ushort As[128 * BK];   // (kc*128 + row)*8
    __shared__ __align__(16) ushort Bs[128 * BK];   // (kc*128 + col)*8
    const int tid = threadIdx.x;
    const int bm = blockIdx.x * 128, bn = blockIdx.y * 128;
    const int lane = tid & 63;
    const int wid = tid >> 6;
    const int wm = wid >> 1, wn = wid & 1;          // wave -> 64x64 quadrant
    const int l16 = lane & 15, lk = lane >> 4;

    const int akc = tid & 3, ar = tid >> 2;
    int arow0 = bm + ar;      arow0 = arow0 < M ? arow0 : M - 1;
    int arow1 = bm + ar + 64; arow1 = arow1 < M ? arow1 : M - 1;
    const int bkc = tid >> 6, bcol = tid & 63;

    f32x4 acc[4][4] = {};
    uint4 pa0, pa1, pb0, pb1;
    auto load_tile = [&](int k0) {
        const ushort* asrc; int ks;
        if (k0 < 256)      { asrc = xhi; ks = k0; }
        else if (k0 < 512) { asrc = xlo; ks = k0 - 256; }
        else               { asrc = xhi; ks = k0 - 512; }
        pa0 = *(const uint4*)(asrc + (size_t)arow0 * 256 + ks + akc * 8);
        pa1 = *(const uint4*)(asrc + (size_t)arow1 * 256 + ks + akc * 8);
        size_t kb = (size_t)((k0 >> 3) + bkc) * 256;
        pb0 = *(const uint4*)(WT2 + (kb + bn + bcol) * 8);
        pb1 = *(const uint4*)(WT2 + (kb + bn + bcol + 64) * 8);
    };
    load_tile(0);
    for (int k0 = 0; k0 < KD; k0 += BK) {
        __syncthreads();
        *(uint4*)(As + (akc * 128 + ar) * 8)        = pa0;
        *(uint4*)(As + (akc * 128 + ar + 64) * 8)   = pa1;
        *(uint4*)(Bs + (bkc * 128 + bcol) * 8)      = pb0;
        *(uint4*)(Bs + (bkc * 128 + bcol + 64) * 8) = pb1;
        __syncthreads();
        if (k0 + BK < KD) load_tile(k0 + BK);
        bf16x8 a[4], b[4];
#pragma unroll
        for (int m = 0; m < 4; m++)
            a[m] = *(const bf16x8*)(As + (lk * 128 + wm * 64 + m * 16 + l16) * 8);
#pragma unroll
        for (int n = 0; n < 4; n++)
            b[n] = *(const bf16x8*)(Bs + (lk * 128 + wn * 64 + n * 16 + l16) * 8);
#pragma unroll
        for (int m = 0; m < 4; m++)
#pragma unroll
            for (int n = 0; n < 4; n++)
                acc[m][n] = __builtin_amdgcn_mfma_f32_16x16x32_bf16(a[m], b[n], acc[m][n], 0, 0, 0);
    }
#pragma unroll
    for (int m = 0; m < 4; m++) {
#pragma unroll
        for (int j = 0; j < 4; j++) {
            int row = bm + wm * 64 + m * 16 + lk * 4 + j;
            if (row < M) {
#pragma unroll
                for (int n = 0; n < 4; n++)
                    h1b[(size_t)row * 256 + bn + wn * 64 + n * 16 + l16] = f2bf(acc[m][n][j]);
            }
        }
    }
}

// ========== GEMM2 (MFMA bf16, split precision): [M,768']x[768',48] ==========
// 4 waves; wave w = 32 rows; acc[2][3] (rows 2x16, cols 3x16, cols 40..47 pad).
__global__ __launch_bounds__(256) void k_gemm2_mfma(const ushort* __restrict__ hi,
                                                    const ushort* __restrict__ lo,
                                                    const ushort* __restrict__ WT,
                                                    ushort* __restrict__ h2, int M) {
    constexpr int BK = 32, KD = 768;
    __shared__ __align__(16) ushort As[128 * BK];   // (kc*128 + row)*8
    __shared__ __align__(16) ushort Bs[48 * BK];    // (kc*48 + col)*8
    const int tid = threadIdx.x;
    const int bm = blockIdx.x * 128;
    const int lane = tid & 63;
    const int w = tid >> 6;
    const int l16 = lane & 15, lk = lane >> 4;

    const int akc = tid & 3, ar = tid >> 2;
    int arow0 = bm + ar;      arow0 = arow0 < M ? arow0 : M - 1;
    int arow1 = bm + ar + 64; arow1 = arow1 < M ? arow1 : M - 1;
    const int bcol = tid % 48, bkc = tid / 48;      // active for tid<192

    f32x4 acc[2][3] = {};
    uint4 pa0, pa1, pb;
    auto load_tile = [&](int k0) {
        const ushort* a; int ks;
        if (k0 < 256)      { a = hi; ks = k0; }
        else if (k0 < 512) { a = lo; ks = k0 - 256; }
        else               { a = hi; ks = k0 - 512; }
        pa0 = *(const uint4*)(a + (size_t)arow0 * 256 + ks + akc * 8);
        pa1 = *(const uint4*)(a + (size_t)arow1 * 256 + ks + akc * 8);
        if (tid < 192)
            pb = *(const uint4*)(WT + ((size_t)((k0 >> 3) + bkc) * 48 + bcol) * 8);
    };
    load_tile(0);
    for (int k0 = 0; k0 < KD; k0 += BK) {
        __syncthreads();
        *(uint4*)(As + (akc * 128 + ar) * 8)      = pa0;
        *(uint4*)(As + (akc * 128 + ar + 64) * 8) = pa1;
        if (tid < 192) *(uint4*)(Bs + (bkc * 48 + bcol) * 8) = pb;
        __syncthreads();
        if (k0 + BK < KD) load_tile(k0 + BK);
        bf16x8 a2[2], b2[3];
#pragma unroll
        for (int m = 0; m < 2; m++)
            a2[m] = *(const bf16x8*)(As + (lk * 128 + w * 32 + m * 16 + l16) * 8);
#pragma unroll
        for (int n = 0; n < 3; n++)
            b2[n] = *(const bf16x8*)(Bs + (lk * 48 + n * 16 + l16) * 8);
#pragma unroll
        for (int m = 0; m < 2; m++)
#pragma unroll
            for (int n = 0; n < 3; n++)
                acc[m][n] = __builtin_amdgcn_mfma_f32_16x16x32_bf16(a2[m], b2[n], acc[m][n], 0, 0, 0);
    }
#pragma unroll
    for (int m = 0; m < 2; m++)
#pragma unroll
        for (int n = 0; n < 3; n++)
#pragma unroll
            for (int j = 0; j < 4; j++) {
                int row = bm + w * 32 + m * 16 + lk * 4 + j;
                int col = n * 16 + l16;
                if (row < M && col < C2)
                    h2[(size_t)row * C2 + col] = f2bf(acc[m][n][j]);
            }
}

// ---------------- per-node attention coefficients (bf16 h) ----------------
template <int H, int C>
__global__ void k_alpha_b(const ushort* __restrict__ h, const float* __restrict__ a_s,
                          const float* __restrict__ a_d, float* __restrict__ asrc,
                          float* __restrict__ adst, int N) {
    __shared__ float ls[H * C], ldd[H * C];
    for (int i = threadIdx.x; i < H * C; i += blockDim.x) { ls[i] = a_s[i]; ldd[i] = a_d[i]; }
    __syncthreads();
    int t = blockIdx.x * blockDim.x + threadIdx.x;
    if (t >= N * H) return;
    int n = t / H, hh = t % H;
    const ushort* row = h + (size_t)n * (H * C) + hh * C;
    float s = 0.f, dd = 0.f;
#pragma unroll
    for (int c = 0; c < C; c += 4) {
        ushort4 v = *(const ushort4*)(row + c);
        float f0 = bf2f(v.x), f1 = bf2f(v.y), f2 = bf2f(v.z), f3 = bf2f(v.w);
        s  += f0 * ls[hh * C + c] + f1 * ls[hh * C + c + 1] +
              f2 * ls[hh * C + c + 2] + f3 * ls[hh * C + c + 3];
        dd += f0 * ldd[hh * C + c] + f1 * ldd[hh * C + c + 1] +
              f2 * ldd[hh * C + c + 2] + f3 * ldd[hh * C + c + 3];
    }
    asrc[t] = s;
    adst[t] = dd;
}

// ======== layer-1 aggregation: half-wave per edge (2 edges/wave-step) ========
// 32 lanes x 16 B cover the 512 B h1b row; halves merged via shfl_xor(32).
// Epilogue emits out1 as bf16 hi/lo (feeds MFMA GEMM2).
__global__ __launch_bounds__(256) void k_gat_aggr1(const int* __restrict__ row_off,
                                                   const int* __restrict__ csr_src,
                                                   const float* __restrict__ asrc,
                                                   const float* __restrict__ adst,
                                                   const ushort* __restrict__ h1b,
                                                   const float* __restrict__ bias,
                                                   ushort* __restrict__ o_hi,
                                                   ushort* __restrict__ o_lo) {
    int wid = (blockIdx.x * 256 + threadIdx.x) >> 6;   // node id
    if (wid >= Nn) return;
    int lane = threadIdx.x & 63;
    int half = lane >> 5, l32 = lane & 31;
    int head = l32 >> 2;                 // 4 lanes per head, 8 ch each
    int c0 = l32 * 8;
    int beg = row_off[wid], end = row_off[wid + 1];
    float ad = adst[(size_t)wid * H1 + head];
    float acc[8] = {};
    float sump = 0.f;
    int i = beg + half;
    for (; i + 2 < end; i += 4) {        // 2 edges per half per iter
        int s0 = csr_src[i], s1 = csr_src[i + 2];
        float a0 = asrc[(size_t)s0 * H1 + head];
        float a1 = asrc[(size_t)s1 * H1 + head];
        bf16x8 v0 = *(const bf16x8*)(h1b + (size_t)s0 * HC1 + c0);
        bf16x8 v1 = *(const bf16x8*)(h1b + (size_t)s1 * HC1 + c0);
        float l0 = a0 + ad; l0 = l0 > 0.f ? l0 : SLOPE * l0;
        float l1 = a1 + ad; l1 = l1 > 0.f ? l1 : SLOPE * l1;
        float p0 = __expf(l0), p1 = __expf(l1);
        sump += p0 + p1;
#pragma unroll
        for (int j = 0; j < 8; j++)
            acc[j] += p0 * bf2f((ushort)v0[j]) + p1 * bf2f((ushort)v1[j]);
    }
    for (; i < end; i += 2) {
        int s = csr_src[i];
        float a = asrc[(size_t)s * H1 + head];
        bf16x8 v = *(const bf16x8*)(h1b + (size_t)s * HC1 + c0);
        float l = a + ad; l = l > 0.f ? l : SLOPE * l;
        float p = __expf(l);
        sump += p;
#pragma unroll
        for (int j = 0; j < 8; j++) acc[j] += p * bf2f((ushort)v[j]);
    }
    // merge the two half-waves
    sump += __shfl_xor(sump, 32);
#pragma unroll
    for (int j = 0; j < 8; j++) acc[j] += __shfl_xor(acc[j], 32);
    if (half) return;
    float inv = 1.f / sump;              // degree >= 1 (self-loop)
    float4 b0 = *(const float4*)(bias + c0);
    float4 b1 = *(const float4*)(bias + c0 + 4);
    float bb[8] = {b0.x, b0.y, b0.z, b0.w, b1.x, b1.y, b1.z, b1.w};
    uint4 uh, ul;
    uint* uhp = (uint*)&uh; uint* ulp = (uint*)&ul;
#pragma unroll
    for (int q = 0; q < 4; q++) {
        float r0 = acc[2 * q] * inv + bb[2 * q];
        float r1 = acc[2 * q + 1] * inv + bb[2 * q + 1];
        r0 = r0 > 0.f ? r0 : __expf(r0) - 1.f;     // fused ELU
        r1 = r1 > 0.f ? r1 : __expf(r1) - 1.f;
        ushort h0 = f2bf(r0), h1v = f2bf(r1);
        ushort l0 = f2bf(r0 - bf2f(h0)), l1v = f2bf(r1 - bf2f(h1v));
        uhp[q] = (uint)h0 | ((uint)h1v << 16);
        ulp[q] = (uint)l0 | ((uint)l1v << 16);
    }
    *(uint4*)(o_hi + (size_t)wid * HC1 + c0) = uh;
    *(uint4*)(o_lo + (size_t)wid * HC1 + c0) = ul;
}

// ======== layer-2 aggregation: wave/node, lanes 0..39, bf16 h2, 4-unrolled ===
__global__ __launch_bounds__(256) void k_gat_aggr2(const int* __restrict__ row_off,
                                                   const int* __restrict__ csr_src,
                                                   const float* __restrict__ asrc,
                                                   const float* __restrict__ adst,
                                                   const ushort* __restrict__ h2,
                                                   const float* __restrict__ bias,
                                                   float* __restrict__ out) {
    int wid = (blockIdx.x * 256 + threadIdx.x) >> 6;
    if (wid >= Nn) return;
    int lane = threadIdx.x & 63;
    int cl = lane < C2 ? lane : C2 - 1;            // clamp: lanes 40..63 read c39
    int beg = row_off[wid], end = row_off[wid + 1];
    float ad = adst[wid];
    float acc = 0.f, sump = 0.f;
    int i = beg;
    for (; i + 3 < end; i += 4) {
        int s0 = csr_src[i], s1 = csr_src[i + 1], s2 = csr_src[i + 2], s3 = csr_src[i + 3];
        float a0 = asrc[s0], a1 = asrc[s1], a2 = asrc[s2], a3 = asrc[s3];
        float v0 = bf2f(h2[(size_t)s0 * C2 + cl]);
        float v1 = bf2f(h2[(size_t)s1 * C2 + cl]);
        float v2 = bf2f(h2[(size_t)s2 * C2 + cl]);
        float v3 = bf2f(h2[(size_t)s3 * C2 + cl]);
        float l0 = a0 + ad; l0 = l0 > 0.f ? l0 : SLOPE * l0;
        float l1 = a1 + ad; l1 = l1 > 0.f ? l1 : SLOPE * l1;
        float l2 = a2 + ad; l2 = l2 > 0.f ? l2 : SLOPE * l2;
        float l3 = a3 + ad; l3 = l3 > 0.f ? l3 : SLOPE * l3;
        float p0 = __expf(l0), p1 = __expf(l1), p2 = __expf(l2), p3 = __expf(l3);
        sump += (p0 + p1) + (p2 + p3);
        acc += p0 * v0 + p1 * v1 + p2 * v2 + p3 * v3;
    }
    for (; i < end; i++) {
        int s = csr_src[i];
        float l = asrc[s] + ad;
        l = l > 0.f ? l : SLOPE * l;
        float pe = __expf(l);
        sump += pe;
        acc += pe * bf2f(h2[(size_t)s * C2 + cl]);
    }
    if (lane < C2) out[(size_t)wid * C2 + lane] = acc / sump + bias[lane];
}

// ---------------- launch ----------------
extern "C" void kernel_launch(void* const* d_in, const int* in_sizes, int n_in,
                              void* d_out, int out_size, void* d_ws, size_t ws_size,
                              hipStream_t stream) {
    const float* x   = (const float*)d_in[0];
    const int*   ei  = (const int*)d_in[1];
    const float* w1  = (const float*)d_in[2];
    const float* as1 = (const float*)d_in[3];
    const float* ad1 = (const float*)d_in[4];
    const float* b1  = (const float*)d_in[5];
    const float* w2  = (const float*)d_in[6];
    const float* as2 = (const float*)d_in[7];
    const float* ad2 = (const float*)d_in[8];
    const float* b2  = (const float*)d_in[9];
    float* outp = (float*)d_out;

    const int* srcA = ei;
    const int* dstA = ei + Ee;

    char* W = (char*)d_ws;
    size_t o = 0;
    auto allocB = [&](size_t bytes) { void* p = W + o; o += (bytes + 255) & ~(size_t)255; return p; };

    ushort* xhi   = (ushort*)allocB((size_t)Nn * HC1 * 2);   // 25.6 MB
    ushort* xlo   = (ushort*)allocB((size_t)Nn * HC1 * 2);   // 25.6 MB
    ushort* o1hi  = xhi;   // alias: out1 hi/lo reuse xhi/xlo after GEMM1
    ushort* o1lo  = xlo;
    ushort* wt2   = (ushort*)allocB((size_t)768 * 256 * 2);  // packed W1'
    ushort* wt2b  = (ushort*)allocB((size_t)768 * 48 * 2);   // packed W2'
    ushort* h1b   = (ushort*)allocB((size_t)Nn * HC1 * 2);   // 25.6 MB
    ushort* h2    = (ushort*)allocB((size_t)Nn * C2 * 2);    // 4 MB (bf16)
    float*  asrc1 = (float*)allocB((size_t)Nn * H1 * 4);
    float*  adst1 = (float*)allocB((size_t)Nn * H1 * 4);
    float*  asrc2 = (float*)allocB((size_t)Nn * 4);
    float*  adst2 = (float*)allocB((size_t)Nn * 4);
    int* counts   = (int*)allocB((size_t)Nn * 4);
    int* exsc     = (int*)allocB((size_t)Nn * 4);
    int* bsum     = (int*)allocB(256 * 4);
    int* boff     = (int*)allocB(256 * 4);
    int* row_off  = (int*)allocB((size_t)(Nn + 1) * 4);
    int* cursor   = (int*)allocB((size_t)Nn * 4);
    int* csr_src  = (int*)allocB((size_t)ETot * 4);

    // ---- input splits (bf16 hi/lo, packed weights) ----
    k_split<<<(Nn * HC1 / 4 + 255) / 256, 256, 0, stream>>>(x, xhi, xlo, Nn * HC1 / 4);
    k_wsplit<<<(256 * 256 + 255) / 256, 256, 0, stream>>>(w1, wt2);
    k_w2split<<<(256 * 48 + 255) / 256, 256, 0, stream>>>(w2, wt2b);

    // ---- CSR build (graph shared by both layers) ----
    hipMemsetAsync(counts, 0, (size_t)Nn * sizeof(int), stream);
    k_hist<<<(ETot + 255) / 256, 256, 0, stream>>>(dstA, counts);
    k_scan_block<<<NB_SCAN, 256, 0, stream>>>(counts, exsc, bsum);
    k_scan_top<<<1, 256, 0, stream>>>(bsum, boff);
    k_finalize_off<<<(Nn + 255) / 256, 256, 0, stream>>>(exsc, boff, row_off, cursor);
    k_scatter<<<(ETot + 255) / 256, 256, 0, stream>>>(srcA, dstA, cursor, csr_src);

    // ---- layer 1 ----
    dim3 g1((Nn + 127) / 128, 2);
    k_gemm1_mfma<<<g1, 256, 0, stream>>>(xhi, xlo, wt2, h1b, Nn);
    k_alpha_b<H1, C1h><<<(Nn * H1 + 255) / 256, 256, 0, stream>>>(h1b, as1, ad1, asrc1, adst1, Nn);
    k_gat_aggr1<<<(int)(((size_t)Nn * 64 + 255) / 256), 256, 0, stream>>>(
        row_off, csr_src, asrc1, adst1, h1b, b1, o1hi, o1lo);

    // ---- layer 2 ----
    k_gemm2_mfma<<<(Nn + 127) / 128, 256, 0, stream>>>(o1hi, o1lo, wt2b, h2, Nn);
    k_alpha_b<1, C2><<<(Nn + 255) / 256, 256, 0, stream>>>(h2, as2, ad2, asrc2, adst2, Nn);
    k_gat_aggr2<<<(int)(((size_t)Nn * 64 + 255) / 256), 256, 0, stream>>>(
        row_off, csr_src, asrc2, adst2, h2, b2, outp);
}